// Round 1
// baseline (994.226 us; speedup 1.0000x reference)
//
#include <hip/hip_runtime.h>

#define BATCH   32768
#define IN_DIM  256
#define OUT_DIM 256
#define NB      9      // basis functions
#define NKNOT   13
#define DEG     3

#define TM 128
#define TN 128
#define IC 8           // input dims staged per K-chunk
#define THREADS 256

// Cox-de-Boor with compile-time knots: open-uniform on [-1,1], 5 internal.
// Fully unrolled; degenerate spans (d1/d2==0) fold away at compile time.
__device__ __forceinline__ void bspline9(float x, float bv[NB]) {
    const float t[NKNOT] = {-1.f, -1.f, -1.f, -1.f,
                            -2.f/3.f, -1.f/3.f, 0.f, 1.f/3.f, 2.f/3.f,
                            1.f, 1.f, 1.f, 1.f};
    float b[NKNOT - 1];
#pragma unroll
    for (int j = 0; j < NKNOT - 1; ++j)
        b[j] = (x >= t[j] && x < t[j + 1]) ? 1.f : 0.f;
    // right endpoint: only span 8 is last nondegenerate span reaching t[-1]
    if (x >= t[NKNOT - 1]) b[8] = 1.f;
#pragma unroll
    for (int d = 1; d <= DEG; ++d) {
#pragma unroll
        for (int j = 0; j < NKNOT - 1 - d; ++j) {
            float d1 = t[j + d] - t[j];
            float d2 = t[j + d + 1] - t[j + 1];
            float w1 = (d1 > 0.f) ? (x - t[j]) * (1.f / d1) : 0.f;
            float w2 = (d2 > 0.f) ? (t[j + d + 1] - x) * (1.f / d2) : 0.f;
            b[j] = w1 * b[j] + w2 * b[j + 1];
        }
    }
#pragma unroll
    for (int r = 0; r < NB; ++r) bv[r] = b[r];
}

// Fused: basis eval -> LDS, coeff tile -> LDS, fp32 outer-product GEMM.
// out[b,o] = sum_i sum_r coeff[o,i,r] * B_r(x[b,i]) + bias[o]
__global__ __launch_bounds__(THREADS) void kan_fused(
        const float* __restrict__ x,
        const float* __restrict__ coeff,
        const float* __restrict__ bias,
        float* __restrict__ out)
{
    // [r][ii][row/col] so the inner GEMM reads contiguous float4 runs
    __shared__ __align__(16) float sb[NB][IC][TM];
    __shared__ __align__(16) float sc[NB][IC][TN];

    const int tid = threadIdx.x;
    const int m0 = blockIdx.x * TM;
    const int n0 = blockIdx.y * TN;
    const int tx = tid & 15;   // n-group: cols tx*8 .. tx*8+7
    const int ty = tid >> 4;   // m-group: rows ty*8 .. ty*8+7

    float acc[8][8];
#pragma unroll
    for (int m = 0; m < 8; ++m)
#pragma unroll
        for (int n = 0; n < 8; ++n) acc[m][n] = 0.f;

    for (int i0 = 0; i0 < IN_DIM; i0 += IC) {
        __syncthreads();
        // ---- stage basis: TM rows x IC input dims, eval 9 splines each ----
#pragma unroll
        for (int q = 0; q < (TM * IC) / THREADS; ++q) {
            int p   = tid + q * THREADS;
            int row = p >> 3;          // p / IC
            int ii  = p & (IC - 1);    // p % IC  (keeps x loads ~coalesced)
            float xv = x[(size_t)(m0 + row) * IN_DIM + (i0 + ii)];
            float bv[NB];
            bspline9(xv, bv);
#pragma unroll
            for (int r = 0; r < NB; ++r) sb[r][ii][row] = bv[r];
        }
        // ---- stage coeff: TN cols x IC dims x NB ----
        for (int p = tid; p < TN * IC * NB; p += THREADS) {
            int col = p / (IC * NB);
            int rem = p - col * (IC * NB);
            int ii  = rem / NB;
            int r   = rem - ii * NB;
            sc[r][ii][col] =
                coeff[(size_t)(n0 + col) * (IN_DIM * NB) + (size_t)(i0 + ii) * NB + r];
        }
        __syncthreads();
        // ---- 8x8 outer-product accumulate ----
#pragma unroll 1
        for (int ii = 0; ii < IC; ++ii) {
#pragma unroll
            for (int r = 0; r < NB; ++r) {
                float4 a0 = *(const float4*)&sb[r][ii][ty * 8];
                float4 a1 = *(const float4*)&sb[r][ii][ty * 8 + 4];
                float4 c0 = *(const float4*)&sc[r][ii][tx * 8];
                float4 c1 = *(const float4*)&sc[r][ii][tx * 8 + 4];
                float am[8] = {a0.x, a0.y, a0.z, a0.w, a1.x, a1.y, a1.z, a1.w};
                float cn[8] = {c0.x, c0.y, c0.z, c0.w, c1.x, c1.y, c1.z, c1.w};
#pragma unroll
                for (int m = 0; m < 8; ++m)
#pragma unroll
                    for (int n = 0; n < 8; ++n)
                        acc[m][n] = fmaf(am[m], cn[n], acc[m][n]);
            }
        }
    }

    float bs[8];
#pragma unroll
    for (int n = 0; n < 8; ++n) bs[n] = bias[n0 + tx * 8 + n];

#pragma unroll
    for (int m = 0; m < 8; ++m) {
        size_t row = (size_t)(m0 + ty * 8 + m);
        float4 o0, o1;
        o0.x = acc[m][0] + bs[0]; o0.y = acc[m][1] + bs[1];
        o0.z = acc[m][2] + bs[2]; o0.w = acc[m][3] + bs[3];
        o1.x = acc[m][4] + bs[4]; o1.y = acc[m][5] + bs[5];
        o1.z = acc[m][6] + bs[6]; o1.w = acc[m][7] + bs[7];
        *(float4*)&out[row * OUT_DIM + n0 + tx * 8]     = o0;
        *(float4*)&out[row * OUT_DIM + n0 + tx * 8 + 4] = o1;
    }
}

extern "C" void kernel_launch(void* const* d_in, const int* in_sizes, int n_in,
                              void* d_out, int out_size, void* d_ws, size_t ws_size,
                              hipStream_t stream) {
    const float* x     = (const float*)d_in[0];   // (32768, 256)
    const float* coeff = (const float*)d_in[1];   // (256, 256, 9)
    const float* bias  = (const float*)d_in[2];   // (256,)
    float* out = (float*)d_out;                   // (32768, 256)

    dim3 grid(BATCH / TM, OUT_DIM / TN);          // 256 x 2 = 512 blocks
    kan_fused<<<grid, dim3(THREADS), 0, stream>>>(x, coeff, bias, out);
}

// Round 2
// 236.592 us; speedup vs baseline: 4.2023x; 4.2023x over previous
//
#include <hip/hip_runtime.h>

#define BATCH   32768
#define IN_DIM  256
#define OUT_DIM 256
#define NB      9      // real basis functions
#define NBP     12     // padded to 12 so BK=96 is a multiple of MFMA K=32
#define NKNOT   13
#define DEG     3

#define TM 128
#define TN 128
#define IC 8                 // input dims per K-chunk
#define BK (IC * NBP)        // 96 padded-k per chunk (3 MFMA k-steps)
#define SAS (BK + 8)         // LDS row stride 104 bf16 = 208 B -> 2-way max bank aliasing (free)
#define THREADS 256

typedef __bf16 bf16x8 __attribute__((ext_vector_type(8)));
typedef float  f32x4  __attribute__((ext_vector_type(4)));

// Cox-de-Boor with compile-time knots — verbatim from the round-1 PASSING kernel.
__device__ __forceinline__ void bspline9(float x, float bv[NB]) {
    const float t[NKNOT] = {-1.f, -1.f, -1.f, -1.f,
                            -2.f/3.f, -1.f/3.f, 0.f, 1.f/3.f, 2.f/3.f,
                            1.f, 1.f, 1.f, 1.f};
    float b[NKNOT - 1];
#pragma unroll
    for (int j = 0; j < NKNOT - 1; ++j)
        b[j] = (x >= t[j] && x < t[j + 1]) ? 1.f : 0.f;
    if (x >= t[NKNOT - 1]) b[8] = 1.f;
#pragma unroll
    for (int d = 1; d <= DEG; ++d) {
#pragma unroll
        for (int j = 0; j < NKNOT - 1 - d; ++j) {
            float d1 = t[j + d] - t[j];
            float d2 = t[j + d + 1] - t[j + 1];
            float w1 = (d1 > 0.f) ? (x - t[j]) * (1.f / d1) : 0.f;
            float w2 = (d2 > 0.f) ? (t[j + d + 1] - x) * (1.f / d2) : 0.f;
            b[j] = w1 * b[j] + w2 * b[j + 1];
        }
    }
#pragma unroll
    for (int r = 0; r < NB; ++r) bv[r] = b[r];
}

// RNE fp32 -> bf16, packed pair into one dword.
__device__ __forceinline__ unsigned packbf2(float a, float b) {
    unsigned ua = __float_as_uint(a);
    unsigned ub = __float_as_uint(b);
    ua += 0x7FFFu + ((ua >> 16) & 1u);
    ub += 0x7FFFu + ((ub >> 16) & 1u);
    return (ua >> 16) | (ub & 0xFFFF0000u);
}

// out[b,o] = sum_i sum_r coeff[o,i,r] * B_r(x[b,i]) + bias[o]
// GEMM view: A = basis[TM][K=3072 padded], B^T = coeff rows; bf16 MFMA 16x16x32.
__global__ __launch_bounds__(THREADS, 3) void kan_mfma(
        const float* __restrict__ x,
        const float* __restrict__ coeff,
        const float* __restrict__ bias,
        float* __restrict__ out)
{
    __shared__ __align__(16) __bf16 sA[TM][SAS];   // 26624 B
    __shared__ __align__(16) __bf16 sB[TN][SAS];   // 26624 B  (53 KB total -> 3 blocks/CU)

    const int tid  = threadIdx.x;
    const int m0   = blockIdx.x * TM;
    const int n0   = blockIdx.y * TN;
    const int lane = tid & 63;
    const int wave = tid >> 6;
    const int wm   = (wave & 1) * 64;   // wave's 64x64 quadrant
    const int wn   = (wave >> 1) * 64;
    const int quad = lane >> 4;
    const int l16  = lane & 15;

    f32x4 acc[4][4] = {};   // [mt][nt], C/D: row = quad*4+reg, col = l16

    for (int i0 = 0; i0 < IN_DIM; i0 += IC) {
        __syncthreads();

        // ---- stage A: basis for TM rows x IC dims, 12 bf16 per (row,ii), 3 pad zeros ----
#pragma unroll
        for (int q = 0; q < (TM * IC) / THREADS; ++q) {   // 4
            int p   = tid + q * THREADS;
            int ii  = p & (IC - 1);
            int row = p >> 3;
            float xv = x[(size_t)(m0 + row) * IN_DIM + i0 + ii];
            float bv[NB];
            bspline9(xv, bv);
            unsigned d0 = packbf2(bv[0], bv[1]);
            unsigned d1 = packbf2(bv[2], bv[3]);
            unsigned d2 = packbf2(bv[4], bv[5]);
            unsigned d3 = packbf2(bv[6], bv[7]);
            unsigned d4 = packbf2(bv[8], 0.f);
            uint2* dst = (uint2*)&sA[row][ii * NBP];   // 8B-aligned (208,24 both %8==0)
            dst[0] = make_uint2(d0, d1);
            dst[1] = make_uint2(d2, d3);
            dst[2] = make_uint2(d4, 0u);
        }

        // ---- stage B: coeff for TN cols x IC dims (9 floats contiguous), pad to 12 ----
#pragma unroll
        for (int q = 0; q < (TN * IC) / THREADS; ++q) {   // 4
            int p   = tid + q * THREADS;
            int ii  = p & (IC - 1);
            int col = p >> 3;
            const float* cp = &coeff[(size_t)(n0 + col) * (IN_DIM * NB)
                                     + (size_t)(i0 + ii) * NB];
            float c0 = cp[0], c1 = cp[1], c2 = cp[2], c3 = cp[3], c4 = cp[4];
            float c5 = cp[5], c6 = cp[6], c7 = cp[7], c8 = cp[8];
            unsigned d0 = packbf2(c0, c1);
            unsigned d1 = packbf2(c2, c3);
            unsigned d2 = packbf2(c4, c5);
            unsigned d3 = packbf2(c6, c7);
            unsigned d4 = packbf2(c8, 0.f);
            uint2* dst = (uint2*)&sB[col][ii * NBP];
            dst[0] = make_uint2(d0, d1);
            dst[1] = make_uint2(d2, d3);
            dst[2] = make_uint2(d4, 0u);
        }

        __syncthreads();

        // ---- MFMA: 3 k-steps x 16 tiles ----
#pragma unroll
        for (int ks = 0; ks < BK / 32; ++ks) {
            bf16x8 af[4], bg[4];
#pragma unroll
            for (int mt = 0; mt < 4; ++mt)
                af[mt] = *(const bf16x8*)&sA[wm + mt * 16 + l16][ks * 32 + quad * 8];
#pragma unroll
            for (int nt = 0; nt < 4; ++nt)
                bg[nt] = *(const bf16x8*)&sB[wn + nt * 16 + l16][ks * 32 + quad * 8];
#pragma unroll
            for (int mt = 0; mt < 4; ++mt)
#pragma unroll
                for (int nt = 0; nt < 4; ++nt)
                    acc[mt][nt] = __builtin_amdgcn_mfma_f32_16x16x32_bf16(
                        af[mt], bg[nt], acc[mt][nt], 0, 0, 0);
        }
    }

    // ---- epilogue: D row = quad*4+reg, col = l16 ----
#pragma unroll
    for (int nt = 0; nt < 4; ++nt) {
        int col = n0 + wn + nt * 16 + l16;
        float bs = bias[col];
#pragma unroll
        for (int mt = 0; mt < 4; ++mt) {
            int row = m0 + wm + mt * 16 + quad * 4;
#pragma unroll
            for (int r = 0; r < 4; ++r)
                out[(size_t)(row + r) * OUT_DIM + col] = acc[mt][nt][r] + bs;
        }
    }
}

extern "C" void kernel_launch(void* const* d_in, const int* in_sizes, int n_in,
                              void* d_out, int out_size, void* d_ws, size_t ws_size,
                              hipStream_t stream) {
    const float* x     = (const float*)d_in[0];   // (32768, 256)
    const float* coeff = (const float*)d_in[1];   // (256, 256, 9)
    const float* bias  = (const float*)d_in[2];   // (256,)
    float* out = (float*)d_out;                   // (32768, 256)

    dim3 grid(BATCH / TM, OUT_DIM / TN);          // 256 x 2
    kan_mfma<<<grid, dim3(THREADS), 0, stream>>>(x, coeff, bias, out);
}